// Round 4
// baseline (19414.931 us; speedup 1.0000x reference)
//
#include <hip/hip_runtime.h>
#include <hip/hip_bf16.h>
#include <math.h>

// ---- model dims ----
#define BSZ 32
#define SEQ 1536
#define DM 256
#define NH 8
#define DH 32
#define MF 110
#define NL 6
#define RB (BSZ*SEQ)          // rows per stream = 49152

#define NRM 0.4204482076268573f      // 32^-0.25
#define HALF_NRM2 0.08838834764831845f  // 0.5/sqrt(32)
#define RATIO 0.09534625892455922f   // 110^-0.5
#define PEPS 1e-4f

__device__ __forceinline__ float wredsum(float v){
  #pragma unroll
  for (int o=32;o;o>>=1) v += __shfl_xor(v,o);
  return v;
}

// ---------------- sentinel: encode ws_size (MB) into d_out for headless diagnosis ----------------
__global__ __launch_bounds__(256) void sentinel_k(float* __restrict__ out, int n, float v)
{
  int i = blockIdx.x*256 + threadIdx.x;
  if (i < n) out[i] = v;
}

// ---------------- embed: build X for one stream ----------------
__global__ __launch_bounds__(256) void embed_k(
    const float* __restrict__ mag, const float* __restrict__ syn,
    const float* __restrict__ magT, const float* __restrict__ synT,
    const float* __restrict__ se, const float* __restrict__ seT,
    float* __restrict__ X, int s)
{
  int tid = threadIdx.x; int w = tid>>6; int lane = tid&63;
  int row = blockIdx.x*4 + w;                 // 0..RB-1
  int b = row / SEQ, t = row % SEQ;
  float val; const float* sep;
  if (!s) {
    int l = t / 192, c = t % 192;
    val = (c < 128) ? mag[((size_t)b*8 + l)*128 + c]
                    : syn[((size_t)b*8 + l)*64 + (c-128)];
    sep = se;
  } else {
    int r = t >> 3, l = t & 7;
    val = (r < 128) ? magT[((size_t)b*128 + r)*8 + l]
                    : synT[((size_t)b*64 + (r-128))*8 + l];
    sep = seT;
  }
  float4 e = *(const float4*)&sep[(size_t)t*DM + lane*4];
  float4 o = make_float4(val*e.x, val*e.y, val*e.z, val*e.w);
  *(float4*)&X[(size_t)row*DM + lane*4] = o;
}

// ---------------- LayerNorm (wave per 256-wide row) ----------------
__global__ __launch_bounds__(256) void ln_k(
    const float* __restrict__ in, float* __restrict__ out,
    const float* __restrict__ sc, const float* __restrict__ sb)
{
  int tid=threadIdx.x, w=tid>>6, lane=tid&63;
  size_t row = (size_t)blockIdx.x*4 + w;
  const float4 v = *(const float4*)&in[row*DM + lane*4];
  float sum = v.x+v.y+v.z+v.w;
  sum = wredsum(sum);
  float mu = sum * (1.f/256.f);
  float dx=v.x-mu, dy=v.y-mu, dz=v.z-mu, dw=v.w-mu;
  float vs = dx*dx+dy*dy+dz*dz+dw*dw;
  vs = wredsum(vs);
  float rstd = rsqrtf(vs*(1.f/256.f) + 1e-5f);
  float4 s4 = *(const float4*)&sc[lane*4];
  float4 b4 = *(const float4*)&sb[lane*4];
  float4 o = make_float4(dx*rstd*s4.x+b4.x, dy*rstd*s4.y+b4.y,
                         dz*rstd*s4.z+b4.z, dw*rstd*s4.w+b4.w);
  *(float4*)&out[row*DM + lane*4] = o;
}

// ---------------- generic tiled fp32 GEMM: C = epi(A@W + bias) ----------------
// A: [RB, K] row-major, W: [K, N] row-major. Tile 128x64, thread 8x4.
// EPI: 0 none, 1 +R1, 2 gelu, 3 0.5*(R1+R2+.)
__global__ __launch_bounds__(256) void gemm_k(
    const float* __restrict__ A, const float* __restrict__ W,
    const float* __restrict__ bias, float* __restrict__ C,
    const float* __restrict__ R1, const float* __restrict__ R2,
    int K, int N, int EPI)
{
  __shared__ float As[16][128];
  __shared__ float Bs[16][64];
  const int tid = threadIdx.x;
  const int tx = tid & 15, ty = tid >> 4;
  const int r0 = blockIdx.y * 128, c0 = blockIdx.x * 64;
  float acc[8][4];
  #pragma unroll
  for (int i=0;i<8;i++){
    #pragma unroll
    for(int j=0;j<4;j++) acc[i][j]=0.f;
  }
  const int ar = tid >> 1;            // 0..127
  const int akq = (tid & 1) * 8;      // 0 or 8
  const int bk = tid >> 4;            // 0..15
  const int bc = (tid & 15) * 4;

  for (int k0 = 0; k0 < K; k0 += 16) {
    float4 a0 = *(const float4*)&A[(size_t)(r0+ar)*K + k0 + akq];
    float4 a1 = *(const float4*)&A[(size_t)(r0+ar)*K + k0 + akq + 4];
    float4 b0 = *(const float4*)&W[(size_t)(k0+bk)*N + c0 + bc];
    As[akq+0][ar]=a0.x; As[akq+1][ar]=a0.y; As[akq+2][ar]=a0.z; As[akq+3][ar]=a0.w;
    As[akq+4][ar]=a1.x; As[akq+5][ar]=a1.y; As[akq+6][ar]=a1.z; As[akq+7][ar]=a1.w;
    *(float4*)&Bs[bk][bc] = b0;
    __syncthreads();
    #pragma unroll
    for (int kk=0;kk<16;kk++) {
      float4 av0 = *(const float4*)&As[kk][ty*8];
      float4 av1 = *(const float4*)&As[kk][ty*8+4];
      float4 bv  = *(const float4*)&Bs[kk][tx*4];
      float a8[8] = {av0.x,av0.y,av0.z,av0.w,av1.x,av1.y,av1.z,av1.w};
      float b4[4] = {bv.x,bv.y,bv.z,bv.w};
      #pragma unroll
      for (int i=0;i<8;i++){
        #pragma unroll
        for (int j=0;j<4;j++) acc[i][j] += a8[i]*b4[j];
      }
    }
    __syncthreads();
  }
  float4 bb = *(const float4*)&bias[c0 + tx*4];
  #pragma unroll
  for (int i=0;i<8;i++){
    size_t row = (size_t)(r0 + ty*8 + i);
    size_t off = row * N + c0 + tx*4;
    float4 v;
    v.x = acc[i][0] + bb.x; v.y = acc[i][1] + bb.y;
    v.z = acc[i][2] + bb.z; v.w = acc[i][3] + bb.w;
    if (EPI == 1) {
      float4 r = *(const float4*)&R1[off];
      v.x += r.x; v.y += r.y; v.z += r.z; v.w += r.w;
    } else if (EPI == 2) {
      v.x = 0.5f*v.x*(1.f+erff(v.x*0.70710678118654752f));
      v.y = 0.5f*v.y*(1.f+erff(v.y*0.70710678118654752f));
      v.z = 0.5f*v.z*(1.f+erff(v.z*0.70710678118654752f));
      v.w = 0.5f*v.w*(1.f+erff(v.w*0.70710678118654752f));
    } else if (EPI == 3) {
      float4 r1 = *(const float4*)&R1[off];
      float4 r2 = *(const float4*)&R2[off];
      v.x = 0.5f*(r1.x + r2.x + v.x); v.y = 0.5f*(r1.y + r2.y + v.y);
      v.z = 0.5f*(r1.z + r2.z + v.z); v.w = 0.5f*(r1.w + r2.w + v.w);
    }
    *(float4*)&C[off] = v;
  }
}

// ---------------- Performer: ctx/ksum per (b,h) ----------------
__global__ __launch_bounds__(128) void ctx_k(
    const float* __restrict__ Kin, const float* __restrict__ Vin,
    const float* __restrict__ proj, float* __restrict__ ctxg,
    float* __restrict__ ksumg)
{
  int h = blockIdx.x, b = blockIdx.y;
  int tid = threadIdx.x;
  __shared__ float Ks[64][32];
  __shared__ float Vs[64][32];
  __shared__ float diag_s[64];
  __shared__ float red[128];
  float pr[32];
  const bool act = tid < MF;
  if (act) {
    #pragma unroll
    for (int d=0; d<32; d++) pr[d] = proj[tid*32+d];
  }
  const float* Kb = Kin + (size_t)b*SEQ*DM + h*32;
  const float* Vb = Vin + (size_t)b*SEQ*DM + h*32;
  // pass 1: global max of xd (stab = NRM * max-dot since NRM>0)
  float mx = -1e30f;
  for (int n0=0;n0<SEQ;n0+=64){
    #pragma unroll
    for (int i=0;i<4;i++){
      int f = tid + i*128;          // float4 index 0..511 (64 rows x 8 f4)
      int r = f >> 3, c4 = (f & 7) * 4;
      *(float4*)&Ks[r][c4] = *(const float4*)&Kb[(size_t)(n0+r)*DM + c4];
    }
    __syncthreads();
    if (act){
      for (int r=0;r<64;r++){
        float dot=0.f;
        #pragma unroll
        for (int d=0;d<32;d++) dot += Ks[r][d]*pr[d];
        mx = fmaxf(mx, dot);
      }
    }
    __syncthreads();
  }
  red[tid] = act ? mx : -1e30f;
  __syncthreads();
  for (int st=64; st; st>>=1){
    if (tid<st) red[tid] = fmaxf(red[tid], red[tid+st]);
    __syncthreads();
  }
  float stab = NRM * red[0];
  // pass 2: accumulate
  float ks_acc = 0.f, cm[32];
  #pragma unroll
  for (int d=0;d<32;d++) cm[d]=0.f;
  for (int n0=0;n0<SEQ;n0+=64){
    #pragma unroll
    for (int i=0;i<4;i++){
      int f = tid + i*128;          // 0..511
      int r = f>>3, c4=(f&7)*4;
      *(float4*)&Ks[r][c4] = *(const float4*)&Kb[(size_t)(n0+r)*DM + c4];
      *(float4*)&Vs[r][c4] = *(const float4*)&Vb[(size_t)(n0+r)*DM + c4];
    }
    __syncthreads();
    if (tid < 64){
      float ss=0.f;
      #pragma unroll
      for (int d=0;d<32;d++) ss += Ks[tid][d]*Ks[tid][d];
      diag_s[tid] = HALF_NRM2 * ss;
    }
    __syncthreads();
    if (act){
      for (int r=0;r<64;r++){
        float dot=0.f;
        #pragma unroll
        for (int d=0;d<32;d++) dot += Ks[r][d]*pr[d];
        float phi = RATIO * (__expf(NRM*dot - diag_s[r] - stab) + PEPS);
        ks_acc += phi;
        #pragma unroll
        for (int d=0;d<32;d++) cm[d] += phi * Vs[r][d];
      }
    }
    __syncthreads();
  }
  if (act){
    size_t base = ((size_t)(b*NH+h)*MF + tid)*32;
    #pragma unroll
    for (int d=0;d<32;d++) ctxg[base+d] = cm[d];
    ksumg[(size_t)(b*NH+h)*MF + tid] = ks_acc;
  }
}

// ---------------- Performer: O = (phi(q)@ctx)/denom per row ----------------
__global__ __launch_bounds__(256) void o_k(
    const float* __restrict__ Qin, const float* __restrict__ proj,
    const float* __restrict__ ctxg, const float* __restrict__ ksumg,
    float* __restrict__ Og)
{
  int n0 = blockIdx.x*64, h = blockIdx.y, b = blockIdx.z;
  int tid=threadIdx.x, w=tid>>6, lane=tid&63;
  __shared__ float proj_s[MF][33];
  __shared__ float ctx_s[MF][33];
  __shared__ float ksum_s[MF];
  __shared__ float qs[4][32];
  __shared__ float phi_s[4][112];
  for (int idx=tid; idx<MF*32; idx+=256){
    proj_s[idx>>5][idx&31] = proj[idx];
    ctx_s[idx>>5][idx&31] = ctxg[(size_t)(b*NH+h)*MF*32 + idx];
  }
  for (int idx=tid; idx<MF; idx+=256) ksum_s[idx] = ksumg[(size_t)(b*NH+h)*MF + idx];
  __syncthreads();
  const int m_a = lane;
  const int m_b = lane + 64;
  const bool hb = (m_b < MF);
  const int half = lane>>5, d2 = lane&31;
  for (int it=0; it<16; it++){
    int n = n0 + it*4 + w;
    size_t qoff = ((size_t)b*SEQ + n)*DM + h*32;
    if (lane < 32) qs[w][lane] = Qin[qoff + lane];
    __syncthreads();
    float ss=0.f;
    #pragma unroll
    for (int d=0;d<32;d++){ float q=qs[w][d]; ss += q*q; }
    float diag = HALF_NRM2 * ss;
    float xa=0.f, xb=0.f;
    #pragma unroll
    for (int d=0;d<32;d++){
      float q = qs[w][d];
      xa += q * proj_s[m_a][d];
      if (hb) xb += q * proj_s[m_b][d];
    }
    xa *= NRM; xb *= NRM;
    float mxv = fmaxf(xa, hb ? xb : -1e30f);
    #pragma unroll
    for (int o=32;o;o>>=1) mxv = fmaxf(mxv, __shfl_xor(mxv,o));
    float pa = RATIO*(__expf(xa - diag - mxv) + PEPS);
    float pb = hb ? RATIO*(__expf(xb - diag - mxv) + PEPS) : 0.f;
    phi_s[w][m_a] = pa;
    if (hb) phi_s[w][m_b] = pb;
    float dn = pa * ksum_s[m_a] + (hb ? pb * ksum_s[m_b] : 0.f);
    dn = wredsum(dn);
    float rden = 1.f / dn;
    float acc = 0.f;
    for (int mm=0; mm<55; mm++){
      int m = half*55 + mm;
      acc += phi_s[w][m] * ctx_s[m][d2];
    }
    acc += __shfl_xor(acc, 32);
    if (lane < 32) Og[qoff + lane] = acc * rden;
    __syncthreads();
  }
}

// ---------------- z accumulation: mode 0: Z = X·fw + fb ; mode 1: Z += perm(X)·fw ----------------
__global__ __launch_bounds__(256) void zacc_k(
    const float* __restrict__ X, const float* __restrict__ fw,
    const float* __restrict__ fb, float* __restrict__ Z, int mode)
{
  int tid=threadIdx.x, w=tid>>6, lane=tid&63;
  int row = blockIdx.x*4 + w;      // 0..RB-1
  int b = row/SEQ, t = row%SEQ;
  int tt = t;
  if (mode == 1) {
    int l = t/192, r = t%192;
    tt = r*8 + l;                  // T-stream token feeding merged position t
  }
  const float4 x0 = *(const float4*)&X[((size_t)b*SEQ + tt)*DM + lane*4];
  const float4 f4 = *(const float4*)&fw[lane*4];
  float ssum = x0.x*f4.x + x0.y*f4.y + x0.z*f4.z + x0.w*f4.w;
  ssum = wredsum(ssum);
  if (lane==0) {
    if (mode == 0) Z[row] = ssum + fb[0];
    else           Z[row] += ssum;
  }
}

// ---------------- out = z @ out_w + out_b ----------------
__global__ __launch_bounds__(256) void out_k(
    const float* __restrict__ Z, const float* __restrict__ outw,
    const float* __restrict__ outb, float* __restrict__ out)
{
  int b = blockIdx.x; int tid = threadIdx.x;
  float4 acc = make_float4(0.f,0.f,0.f,0.f);
  const float* zrow = Z + (size_t)b*SEQ;
  for (int t=0;t<SEQ;t++){
    float zv = zrow[t];
    float4 wv = *(const float4*)&outw[(size_t)t*1024 + tid*4];
    acc.x += zv*wv.x; acc.y += zv*wv.y; acc.z += zv*wv.z; acc.w += zv*wv.w;
  }
  float4 ob = *(const float4*)&outb[tid*4];
  float4 o = make_float4(acc.x+ob.x, acc.y+ob.y, acc.z+ob.z, acc.w+ob.w);
  *(float4*)&out[(size_t)b*1024 + tid*4] = o;
}

extern "C" void kernel_launch(void* const* d_in, const int* in_sizes, int n_in,
                              void* d_out, int out_size, void* d_ws, size_t ws_size,
                              hipStream_t stream) {
  (void)in_sizes; (void)n_in;
  const float* mag  = (const float*)d_in[0];
  const float* syn  = (const float*)d_in[1];
  const float* magT = (const float*)d_in[2];
  const float* synT = (const float*)d_in[3];
  const float* se   = (const float*)d_in[4];
  const float* seT  = (const float*)d_in[5];
  const float* ln1s = (const float*)d_in[6];
  const float* ln1b = (const float*)d_in[7];
  const float* Wq   = (const float*)d_in[8];
  const float* bq   = (const float*)d_in[9];
  const float* Wk   = (const float*)d_in[10];
  const float* bk   = (const float*)d_in[11];
  const float* Wv   = (const float*)d_in[12];
  const float* bv   = (const float*)d_in[13];
  const float* Wo   = (const float*)d_in[14];
  const float* bo   = (const float*)d_in[15];
  const float* proj = (const float*)d_in[16];
  const float* ln2s = (const float*)d_in[17];
  const float* ln2b = (const float*)d_in[18];
  const float* W1   = (const float*)d_in[19];
  const float* b1   = (const float*)d_in[20];
  const float* W2   = (const float*)d_in[21];
  const float* b2   = (const float*)d_in[22];
  const float* fw   = (const float*)d_in[23];
  const float* fb   = (const float*)d_in[24];
  const float* outw = (const float*)d_in[25];
  const float* outb = (const float*)d_in[26];
  float* out = (float*)d_out;

  float* ws = (float*)d_ws;
  const size_t PANEL = (size_t)RB*DM;        // 12.58M floats
  size_t oX  = 0;                            // X: current stream state
  size_t oP0 = oX  + PANEL;                  // H / O / H2
  size_t oP1 = oP0 + PANEL;                  // Q / Y1
  size_t oP2 = oP1 + PANEL;                  // K / FFI[:,0:256] (FFI spans P2+P3)
  size_t oP3 = oP2 + PANEL;                  // V / FFI[:,256:512]
  size_t oCTX = oP3 + PANEL;                 // [256,110,32]
  size_t oKS  = oCTX + (size_t)256*MF*32;    // [256,110]
  size_t oZ   = oKS + (size_t)256*MF;        // [32,1536]
  size_t needed = (oZ + (size_t)BSZ*SEQ) * sizeof(float);   // ~255.6 MB
  if (ws_size < needed) {
    // diagnostic sentinel: absmax will read ~100000 + ws_size_in_MB
    float v = 100000.0f + (float)(ws_size >> 20);
    sentinel_k<<<dim3((out_size+255)/256), 256, 0, stream>>>(out, out_size, v);
    return;
  }
  float* X  = ws+oX; float* P0 = ws+oP0; float* P1 = ws+oP1;
  float* P2 = ws+oP2; float* P3 = ws+oP3;
  float* CTXb = ws+oCTX; float* KSb = ws+oKS; float* Zb = ws+oZ;

  for (int s=0; s<2; s++){
    embed_k<<<dim3(RB/4), 256, 0, stream>>>(mag, syn, magT, synT, se, seT, X, s);
    for (int l=0; l<NL; l++){
      int wi = s*NL + l;
      const float* pWq = Wq + (size_t)wi*DM*DM;
      const float* pWk = Wk + (size_t)wi*DM*DM;
      const float* pWv = Wv + (size_t)wi*DM*DM;
      const float* pWo = Wo + (size_t)wi*DM*DM;
      const float* pW1 = W1 + (size_t)wi*DM*512;
      const float* pW2 = W2 + (size_t)wi*512*DM;
      const float* pproj = proj + (size_t)wi*MF*DH;

      // H = LN1(X) -> P0
      ln_k<<<dim3(RB/4), 256, 0, stream>>>(X, P0, ln1s + (size_t)wi*DM, ln1b + (size_t)wi*DM);
      // Q,K,V = H@W + b -> P1,P2,P3
      gemm_k<<<dim3(4,384), 256, 0, stream>>>(P0, pWq, bq + (size_t)wi*DM, P1, nullptr, nullptr, 256, 256, 0);
      gemm_k<<<dim3(4,384), 256, 0, stream>>>(P0, pWk, bk + (size_t)wi*DM, P2, nullptr, nullptr, 256, 256, 0);
      gemm_k<<<dim3(4,384), 256, 0, stream>>>(P0, pWv, bv + (size_t)wi*DM, P3, nullptr, nullptr, 256, 256, 0);
      // ctx/ksum per (b,h)
      ctx_k<<<dim3(NH,BSZ), 128, 0, stream>>>(P2, P3, pproj, CTXb, KSb);
      // O -> P0 (H consumed)
      o_k<<<dim3(SEQ/64, NH, BSZ), 256, 0, stream>>>(P1, pproj, CTXb, KSb, P0);
      // Y1 = X + O@Wo + bo -> P1 (Q consumed)
      gemm_k<<<dim3(4,384), 256, 0, stream>>>(P0, pWo, bo + (size_t)wi*DM, P1, X, nullptr, 256, 256, 1);
      // H2 = LN2(Y1) -> P0 (O consumed)
      ln_k<<<dim3(RB/4), 256, 0, stream>>>(P1, P0, ln2s + (size_t)wi*DM, ln2b + (size_t)wi*DM);
      // FFI = gelu(H2@W1 + b1) -> P2..P3 (512-wide, contiguous)
      gemm_k<<<dim3(8,384), 256, 0, stream>>>(P0, pW1, b1 + (size_t)wi*512, P2, nullptr, nullptr, 256, 512, 2);
      // X = 0.5*(X + Y1 + FFI@W2 + b2)  (in place)
      gemm_k<<<dim3(4,384), 256, 0, stream>>>(P2, pW2, b2 + (size_t)wi*DM, X, X, P1, 512, 256, 3);
    }
    // fold this stream's head contribution into Z
    zacc_k<<<dim3(RB/4), 256, 0, stream>>>(X, fw, fb, Zb, s);
  }

  out_k<<<dim3(BSZ), 256, 0, stream>>>(Zb, outw, outb, out);
}

// Round 5
// 16953.584 us; speedup vs baseline: 1.1452x; 1.1452x over previous
//
#include <hip/hip_runtime.h>
#include <hip/hip_bf16.h>
#include <math.h>

// ---- model dims ----
#define BSZ 32
#define SEQ 1536
#define DM 256
#define NH 8
#define DH 32
#define MF 110
#define NL 6
#define RB (BSZ*SEQ)          // rows per stream = 49152
#define NCH 12
#define CH (SEQ/NCH)          // 128 rows per attention chunk

#define NRM 0.4204482076268573f         // 32^-0.25
#define HALF_NRM2 0.08838834764831845f  // 0.5/sqrt(32)
#define RATIO 0.09534625892455922f      // 110^-0.5
#define PEPS 1e-4f

typedef unsigned short u16;
using short8v = __attribute__((ext_vector_type(8))) short;
using f32x4   = __attribute__((ext_vector_type(4))) float;

#define GLOAD_LDS16(g, l) __builtin_amdgcn_global_load_lds( \
    (const __attribute__((address_space(1))) void*)(g), \
    (__attribute__((address_space(3))) void*)(l), 16, 0, 0)

__device__ __forceinline__ float wredsum(float v){
  #pragma unroll
  for (int o=32;o;o>>=1) v += __shfl_xor(v,o);
  return v;
}
__device__ __forceinline__ u16 f2bf(float x){
  unsigned u = __float_as_uint(x);
  return (u16)((u + 0x7FFFu + ((u>>16)&1u)) >> 16);
}
__device__ __forceinline__ float b2f(u16 h){
  return __uint_as_float(((unsigned)h)<<16);
}

// ---------------- sentinel ----------------
__global__ __launch_bounds__(256) void sentinel_k(float* __restrict__ out, int n, float v)
{
  int i = blockIdx.x*256 + threadIdx.x;
  if (i < n) out[i] = v;
}

// ---------------- weight transpose+convert: src fp32 [L][K][N] -> dst bf16 [L][N][K] ----------------
__global__ __launch_bounds__(256) void wtrans_k(
    const float* __restrict__ src, u16* __restrict__ dst,
    int K, int N, size_t dstStride)
{
  int l = blockIdx.z;
  const float* s = src + (size_t)l*K*N;
  u16* d = dst + (size_t)l*dstStride;
  __shared__ float t[32][33];
  int k0 = blockIdx.y*32, n0 = blockIdx.x*32;
  int tx = threadIdx.x & 31, ty = threadIdx.x >> 5;   // 32 x 8
  #pragma unroll
  for (int i=0;i<32;i+=8) t[ty+i][tx] = s[(size_t)(k0+ty+i)*N + n0+tx];
  __syncthreads();
  #pragma unroll
  for (int i=0;i<32;i+=8) d[(size_t)(n0+ty+i)*K + k0+tx] = f2bf(t[tx][ty+i]);
}

// ---------------- embed: build X (fp32) for one stream ----------------
__global__ __launch_bounds__(256) void embed_k(
    const float* __restrict__ mag, const float* __restrict__ syn,
    const float* __restrict__ magT, const float* __restrict__ synT,
    const float* __restrict__ se, const float* __restrict__ seT,
    float* __restrict__ X, int s)
{
  int tid = threadIdx.x; int w = tid>>6; int lane = tid&63;
  int row = blockIdx.x*4 + w;
  int b = row / SEQ, t = row % SEQ;
  float val; const float* sep;
  if (!s) {
    int l = t / 192, c = t % 192;
    val = (c < 128) ? mag[((size_t)b*8 + l)*128 + c]
                    : syn[((size_t)b*8 + l)*64 + (c-128)];
    sep = se;
  } else {
    int r = t >> 3, l = t & 7;
    val = (r < 128) ? magT[((size_t)b*128 + r)*8 + l]
                    : synT[((size_t)b*64 + (r-128))*8 + l];
    sep = seT;
  }
  float4 e = *(const float4*)&sep[(size_t)t*DM + lane*4];
  float4 o = make_float4(val*e.x, val*e.y, val*e.z, val*e.w);
  *(float4*)&X[(size_t)row*DM + lane*4] = o;
}

// ---------------- LayerNorm: fp32 in -> bf16 out ----------------
__global__ __launch_bounds__(256) void ln_k(
    const float* __restrict__ in, u16* __restrict__ out,
    const float* __restrict__ sc, const float* __restrict__ sb)
{
  int tid=threadIdx.x, w=tid>>6, lane=tid&63;
  size_t row = (size_t)blockIdx.x*4 + w;
  const float4 v = *(const float4*)&in[row*DM + lane*4];
  float sum = v.x+v.y+v.z+v.w;
  sum = wredsum(sum);
  float mu = sum * (1.f/256.f);
  float dx=v.x-mu, dy=v.y-mu, dz=v.z-mu, dw=v.w-mu;
  float vs = dx*dx+dy*dy+dz*dz+dw*dw;
  vs = wredsum(vs);
  float rstd = rsqrtf(vs*(1.f/256.f) + 1e-5f);
  float4 s4 = *(const float4*)&sc[lane*4];
  float4 b4 = *(const float4*)&sb[lane*4];
  ushort4 o;
  o.x = f2bf(dx*rstd*s4.x+b4.x); o.y = f2bf(dy*rstd*s4.y+b4.y);
  o.z = f2bf(dz*rstd*s4.z+b4.z); o.w = f2bf(dw*rstd*s4.w+b4.w);
  *(ushort4*)&out[row*DM + lane*4] = o;
}

// ---------------- MFMA GEMM: C = epi(A@Wt^T + bias) ----------------
// A: [M,K] bf16 row-major. Wt: [N,K] bf16 row-major. Tile 128x64, 4 waves 2x2.
// EPI: 0 -> bf16 out; 1 -> f32 out (+R1); 2 -> bf16 out gelu; 3 -> f32 out 0.5*(R1+R2+.)
__global__ __launch_bounds__(256) void mgemm_k(
    const u16* __restrict__ A, const u16* __restrict__ Wt,
    const float* __restrict__ bias, void* __restrict__ Cout,
    const float* __restrict__ R1, const float* __restrict__ R2,
    int K, int N, int EPI)
{
  __shared__ u16 As[128*32];   // [row][k] linear, 64B rows
  __shared__ u16 Bs[64*32];    // [col][k] linear
  const int tid = threadIdx.x;
  const int lane = tid & 63, w = tid >> 6;
  const int wr = w >> 1, wc = w & 1;
  const int r0 = blockIdx.y*128, c0 = blockIdx.x*64;

  f32x4 acc[4][2];
  #pragma unroll
  for (int m=0;m<4;m++){
    #pragma unroll
    for (int n=0;n<2;n++) acc[m][n] = (f32x4){0.f,0.f,0.f,0.f};
  }
  const int lr = lane>>2;          // 0..15 row-in-chunk
  const int lk = (lane&3)*8;       // k offset
  for (int k0 = 0; k0 < K; k0 += 32){
    // A: wave w stages rows [w*32, w*32+32)
    GLOAD_LDS16(&A[(size_t)(r0 + w*32      + lr)*K + k0 + lk], &As[(w*32     )*32]);
    GLOAD_LDS16(&A[(size_t)(r0 + w*32 + 16 + lr)*K + k0 + lk], &As[(w*32 + 16)*32]);
    // B: wave w stages cols [w*16, w*16+16)
    GLOAD_LDS16(&Wt[(size_t)(c0 + w*16 + lr)*K + k0 + lk], &Bs[(w*16)*32]);
    __syncthreads();
    short8v a[4], bq[2];
    #pragma unroll
    for (int m=0;m<4;m++)
      a[m] = *(const short8v*)&As[(wr*64 + m*16 + (lane&15))*32 + (lane>>4)*8];
    #pragma unroll
    for (int n=0;n<2;n++)
      bq[n] = *(const short8v*)&Bs[(wc*32 + n*16 + (lane&15))*32 + (lane>>4)*8];
    #pragma unroll
    for (int m=0;m<4;m++){
      #pragma unroll
      for (int n=0;n<2;n++)
        acc[m][n] = __builtin_amdgcn_mfma_f32_16x16x32_bf16(a[m], bq[n], acc[m][n], 0,0,0);
    }
    __syncthreads();
  }
  // epilogue: D row = (lane>>4)*4 + i, col = lane&15  (m89-verified)
  const int cb = c0 + wc*32 + (lane&15);
  const int rb = r0 + wr*64 + (lane>>4)*4;
  #pragma unroll
  for (int m=0;m<4;m++){
    #pragma unroll
    for (int n=0;n<2;n++){
      int c = cb + n*16;
      float bb = bias[c];
      #pragma unroll
      for (int i=0;i<4;i++){
        int r = rb + m*16 + i;
        size_t off = (size_t)r*N + c;
        float v = acc[m][n][i] + bb;
        if (EPI == 0) {
          ((u16*)Cout)[off] = f2bf(v);
        } else if (EPI == 1) {
          ((float*)Cout)[off] = v + R1[off];
        } else if (EPI == 2) {
          v = 0.5f*v*(1.f+erff(v*0.70710678118654752f));
          ((u16*)Cout)[off] = f2bf(v);
        } else {
          ((float*)Cout)[off] = 0.5f*(R1[off] + R2[off] + v);
        }
      }
    }
  }
}

// ---------------- zero ctx/ksum ----------------
__global__ __launch_bounds__(256) void zero_k(float* __restrict__ p, int n)
{
  int i = blockIdx.x*256 + threadIdx.x;
  if (i < n) p[i] = 0.f;
}

// ---------------- Performer: chunk max of K-dot per (b,h,chunk) ----------------
__global__ __launch_bounds__(128) void ctxmax_k(
    const u16* __restrict__ Kin, const float* __restrict__ proj,
    float* __restrict__ pmax)
{
  int h = blockIdx.x, b = blockIdx.y, ch = blockIdx.z;
  int tid = threadIdx.x;
  __shared__ float Ks[CH][33];
  __shared__ float red[128];
  const u16* Kb = Kin + ((size_t)b*SEQ + ch*CH)*DM + h*32;
  #pragma unroll
  for (int i=0;i<4;i++){
    int f = tid + i*128;            // short8 units: CH*4
    int r = f >> 2, c8 = (f & 3)*8;
    short8v v = *(const short8v*)&Kb[(size_t)r*DM + c8];
    #pragma unroll
    for (int j=0;j<8;j++) Ks[r][c8+j] = b2f((u16)v[j]);
  }
  __syncthreads();
  float mx = -1e30f;
  if (tid < MF){
    float pr[32];
    #pragma unroll
    for (int d=0;d<32;d++) pr[d] = proj[tid*32+d];
    for (int r=0;r<CH;r++){
      float dot=0.f;
      #pragma unroll
      for (int d=0;d<32;d++) dot += Ks[r][d]*pr[d];
      mx = fmaxf(mx, dot);
    }
  }
  red[tid] = mx;
  __syncthreads();
  for (int st=64; st; st>>=1){
    if (tid<st) red[tid] = fmaxf(red[tid], red[tid+st]);
    __syncthreads();
  }
  if (tid==0) pmax[(size_t)(b*NH+h)*NCH + ch] = red[0];
}

// ---------------- Performer: chunk ctx/ksum accumulate (atomic merge) ----------------
__global__ __launch_bounds__(128) void ctxacc_k(
    const u16* __restrict__ Kin, const u16* __restrict__ Vin,
    const float* __restrict__ proj, const float* __restrict__ pmax,
    float* __restrict__ ctxg, float* __restrict__ ksumg)
{
  int h = blockIdx.x, b = blockIdx.y, ch = blockIdx.z;
  int tid = threadIdx.x;
  int bh = b*NH + h;
  __shared__ float Ks[CH][33];
  __shared__ float Vs[CH][33];
  __shared__ float diag_s[CH];
  const u16* Kb = Kin + ((size_t)b*SEQ + ch*CH)*DM + h*32;
  const u16* Vb = Vin + ((size_t)b*SEQ + ch*CH)*DM + h*32;
  #pragma unroll
  for (int i=0;i<4;i++){
    int f = tid + i*128;
    int r = f >> 2, c8 = (f & 3)*8;
    short8v vk = *(const short8v*)&Kb[(size_t)r*DM + c8];
    short8v vv = *(const short8v*)&Vb[(size_t)r*DM + c8];
    #pragma unroll
    for (int j=0;j<8;j++){ Ks[r][c8+j] = b2f((u16)vk[j]); Vs[r][c8+j] = b2f((u16)vv[j]); }
  }
  __syncthreads();
  {
    float ss=0.f;
    #pragma unroll
    for (int d=0;d<32;d++){ float k=Ks[tid][d]; ss += k*k; }
    diag_s[tid] = HALF_NRM2 * ss;
  }
  float gm = -1e30f;
  #pragma unroll
  for (int c=0;c<NCH;c++) gm = fmaxf(gm, pmax[(size_t)bh*NCH + c]);
  float stab = NRM * gm;
  __syncthreads();
  if (tid < MF){
    float pr[32], cm[32];
    #pragma unroll
    for (int d=0;d<32;d++){ pr[d] = proj[tid*32+d]; cm[d]=0.f; }
    float ks = 0.f;
    for (int r=0;r<CH;r++){
      float dot=0.f;
      #pragma unroll
      for (int d=0;d<32;d++) dot += Ks[r][d]*pr[d];
      float phi = RATIO * (__expf(NRM*dot - diag_s[r] - stab) + PEPS);
      ks += phi;
      #pragma unroll
      for (int d=0;d<32;d++) cm[d] += phi * Vs[r][d];
    }
    atomicAdd(&ksumg[(size_t)bh*MF + tid], ks);
    size_t base = ((size_t)bh*MF + tid)*32;
    #pragma unroll
    for (int d=0;d<32;d++) atomicAdd(&ctxg[base+d], cm[d]);
  }
}

// ---------------- Performer: O = (phi(q)@ctx)/denom per row (bf16 Q in, bf16 O out) ----------------
__global__ __launch_bounds__(256) void o_k(
    const u16* __restrict__ Qin, const float* __restrict__ proj,
    const float* __restrict__ ctxg, const float* __restrict__ ksumg,
    u16* __restrict__ Og)
{
  int n0 = blockIdx.x*64, h = blockIdx.y, b = blockIdx.z;
  int tid=threadIdx.x, w=tid>>6, lane=tid&63;
  __shared__ float proj_s[MF][33];
  __shared__ float ctx_s[MF][33];
  __shared__ float ksum_s[MF];
  __shared__ float qs[4][32];
  __shared__ float phi_s[4][112];
  for (int idx=tid; idx<MF*32; idx+=256){
    proj_s[idx>>5][idx&31] = proj[idx];
    ctx_s[idx>>5][idx&31] = ctxg[(size_t)(b*NH+h)*MF*32 + idx];
  }
  for (int idx=tid; idx<MF; idx+=256) ksum_s[idx] = ksumg[(size_t)(b*NH+h)*MF + idx];
  __syncthreads();
  const int m_a = lane;
  const int m_b = lane + 64;
  const bool hb = (m_b < MF);
  const int half = lane>>5, d2 = lane&31;
  for (int it=0; it<16; it++){
    int n = n0 + it*4 + w;
    size_t qoff = ((size_t)b*SEQ + n)*DM + h*32;
    if (lane < 32) qs[w][lane] = b2f(Qin[qoff + lane]);
    __syncthreads();
    float ss=0.f;
    #pragma unroll
    for (int d=0;d<32;d++){ float q=qs[w][d]; ss += q*q; }
    float diag = HALF_NRM2 * ss;
    float xa=0.f, xb=0.f;
    #pragma unroll
    for (int d=0;d<32;d++){
      float q = qs[w][d];
      xa += q * proj_s[m_a][d];
      if (hb) xb += q * proj_s[m_b][d];
    }
    xa *= NRM; xb *= NRM;
    float mxv = fmaxf(xa, hb ? xb : -1e30f);
    #pragma unroll
    for (int o=32;o;o>>=1) mxv = fmaxf(mxv, __shfl_xor(mxv,o));
    float pa = RATIO*(__expf(xa - diag - mxv) + PEPS);
    float pb = hb ? RATIO*(__expf(xb - diag - mxv) + PEPS) : 0.f;
    phi_s[w][m_a] = pa;
    if (hb) phi_s[w][m_b] = pb;
    float dn = pa * ksum_s[m_a] + (hb ? pb * ksum_s[m_b] : 0.f);
    dn = wredsum(dn);
    float rden = 1.f / dn;
    float acc = 0.f;
    for (int mm=0; mm<55; mm++){
      int m = half*55 + mm;
      acc += phi_s[w][m] * ctx_s[m][d2];
    }
    acc += __shfl_xor(acc, 32);
    if (lane < 32) Og[qoff + lane] = f2bf(acc * rden);
    __syncthreads();
  }
}

// ---------------- z accumulation ----------------
__global__ __launch_bounds__(256) void zacc_k(
    const float* __restrict__ X, const float* __restrict__ fw,
    const float* __restrict__ fb, float* __restrict__ Z, int mode)
{
  int tid=threadIdx.x, w=tid>>6, lane=tid&63;
  int row = blockIdx.x*4 + w;
  int b = row/SEQ, t = row%SEQ;
  int tt = t;
  if (mode == 1) {
    int l = t/192, r = t%192;
    tt = r*8 + l;
  }
  const float4 x0 = *(const float4*)&X[((size_t)b*SEQ + tt)*DM + lane*4];
  const float4 f4 = *(const float4*)&fw[lane*4];
  float ssum = x0.x*f4.x + x0.y*f4.y + x0.z*f4.z + x0.w*f4.w;
  ssum = wredsum(ssum);
  if (lane==0) {
    if (mode == 0) Z[row] = ssum + fb[0];
    else           Z[row] += ssum;
  }
}

// ---------------- out = z @ out_w + out_b ----------------
__global__ __launch_bounds__(256) void out_k(
    const float* __restrict__ Z, const float* __restrict__ outw,
    const float* __restrict__ outb, float* __restrict__ out)
{
  int b = blockIdx.x; int tid = threadIdx.x;
  float4 acc = make_float4(0.f,0.f,0.f,0.f);
  const float* zrow = Z + (size_t)b*SEQ;
  for (int t=0;t<SEQ;t++){
    float zv = zrow[t];
    float4 wv = *(const float4*)&outw[(size_t)t*1024 + tid*4];
    acc.x += zv*wv.x; acc.y += zv*wv.y; acc.z += zv*wv.z; acc.w += zv*wv.w;
  }
  float4 ob = *(const float4*)&outb[tid*4];
  float4 o = make_float4(acc.x+ob.x, acc.y+ob.y, acc.z+ob.z, acc.w+ob.w);
  *(float4*)&out[(size_t)b*1024 + tid*4] = o;
}

extern "C" void kernel_launch(void* const* d_in, const int* in_sizes, int n_in,
                              void* d_out, int out_size, void* d_ws, size_t ws_size,
                              hipStream_t stream) {
  (void)in_sizes; (void)n_in;
  const float* mag  = (const float*)d_in[0];
  const float* syn  = (const float*)d_in[1];
  const float* magT = (const float*)d_in[2];
  const float* synT = (const float*)d_in[3];
  const float* se   = (const float*)d_in[4];
  const float* seT  = (const float*)d_in[5];
  const float* ln1s = (const float*)d_in[6];
  const float* ln1b = (const float*)d_in[7];
  const float* Wq   = (const float*)d_in[8];
  const float* bq   = (const float*)d_in[9];
  const float* Wk   = (const float*)d_in[10];
  const float* bk   = (const float*)d_in[11];
  const float* Wv   = (const float*)d_in[12];
  const float* bv   = (const float*)d_in[13];
  const float* Wo   = (const float*)d_in[14];
  const float* bo   = (const float*)d_in[15];
  const float* proj = (const float*)d_in[16];
  const float* ln2s = (const float*)d_in[17];
  const float* ln2b = (const float*)d_in[18];
  const float* W1   = (const float*)d_in[19];
  const float* b1   = (const float*)d_in[20];
  const float* W2   = (const float*)d_in[21];
  const float* b2   = (const float*)d_in[22];
  const float* fw   = (const float*)d_in[23];
  const float* fb   = (const float*)d_in[24];
  const float* outw = (const float*)d_in[25];
  const float* outb = (const float*)d_in[26];
  float* out = (float*)d_out;

  // ---- workspace layout (bytes) ----
  char* base = (char*)d_ws;
  const size_t PANEL = (size_t)RB*DM;               // elements
  size_t off = 0;
  float* X   = (float*)(base + off); off += PANEL*4;
  float* Y1  = (float*)(base + off); off += PANEL*4;
  u16*  Hb   = (u16*)(base + off);   off += PANEL*2;
  u16*  Qb   = (u16*)(base + off);   off += PANEL*2;   // FFI = Qb spanning Qb+Kb (RB x 512)
  u16*  Kb   = (u16*)(base + off);   off += PANEL*2;
  u16*  Vb   = (u16*)(base + off);   off += PANEL*2;
  u16*  Wts  = (u16*)(base + off);   off += (size_t)12*524288*2;
  float* CTXb= (float*)(base + off); off += (size_t)256*MF*32*4;
  float* KSb = (float*)(base + off); off += (size_t)256*MF*4;
  float* PMb = (float*)(base + off); off += (size_t)256*NCH*4;
  float* Zb  = (float*)(base + off); off += (size_t)BSZ*SEQ*4;
  if (ws_size < off) {
    float v = 100000.0f + (float)(ws_size >> 20);
    sentinel_k<<<dim3((out_size+255)/256), 256, 0, stream>>>(out, out_size, v);
    return;
  }
  // per-layer Wt sublayout: [Wqt 65536][Wkt][Wvt][Wot][W1t 131072][W2t 131072], stride 524288
  const size_t WST = 524288;

  // ---- transpose+convert all weights (both streams, 12 layers) ----
  wtrans_k<<<dim3(8,8,12),  256, 0, stream>>>(Wq, Wts + 0,      256, 256, WST);
  wtrans_k<<<dim3(8,8,12),  256, 0, stream>>>(Wk, Wts + 65536,  256, 256, WST);
  wtrans_k<<<dim3(8,8,12),  256, 0, stream>>>(Wv, Wts + 131072, 256, 256, WST);
  wtrans_k<<<dim3(8,8,12),  256, 0, stream>>>(Wo, Wts + 196608, 256, 256, WST);
  wtrans_k<<<dim3(16,8,12), 256, 0, stream>>>(W1, Wts + 262144, 256, 512, WST);
  wtrans_k<<<dim3(8,16,12), 256, 0, stream>>>(W2, Wts + 393216, 512, 256, WST);

  const int NZ = 256*MF*32 + 256*MF;
  for (int s=0; s<2; s++){
    embed_k<<<dim3(RB/4), 256, 0, stream>>>(mag, syn, magT, synT, se, seT, X, s);
    for (int l=0; l<NL; l++){
      int wi = s*NL + l;
      const u16* Wqt = Wts + (size_t)wi*WST;
      const u16* Wkt = Wqt + 65536;
      const u16* Wvt = Wqt + 131072;
      const u16* Wot = Wqt + 196608;
      const u16* W1t = Wqt + 262144;
      const u16* W2t = Wqt + 393216;
      const float* pproj = proj + (size_t)wi*MF*DH;

      // H = LN1(X) -> Hb (bf16)
      ln_k<<<dim3(RB/4), 256, 0, stream>>>(X, Hb, ln1s + (size_t)wi*DM, ln1b + (size_t)wi*DM);
      // Q,K,V
      mgemm_k<<<dim3(4,384), 256, 0, stream>>>(Hb, Wqt, bq + (size_t)wi*DM, Qb, nullptr, nullptr, 256, 256, 0);
      mgemm_k<<<dim3(4,384), 256, 0, stream>>>(Hb, Wkt, bk + (size_t)wi*DM, Kb, nullptr, nullptr, 256, 256, 0);
      mgemm_k<<<dim3(4,384), 256, 0, stream>>>(Hb, Wvt, bv + (size_t)wi*DM, Vb, nullptr, nullptr, 256, 256, 0);
      // attention ctx/ksum (chunk-parallel)
      zero_k<<<dim3((NZ+255)/256), 256, 0, stream>>>(CTXb, NZ);   // CTXb & KSb contiguous
      ctxmax_k<<<dim3(NH,BSZ,NCH), 128, 0, stream>>>(Kb, pproj, PMb);
      ctxacc_k<<<dim3(NH,BSZ,NCH), 128, 0, stream>>>(Kb, Vb, pproj, PMb, CTXb, KSb);
      // O -> Hb (bf16, H consumed)
      o_k<<<dim3(SEQ/64, NH, BSZ), 256, 0, stream>>>(Qb, pproj, CTXb, KSb, Hb);
      // Y1 = X + O@Wo + bo (fp32)
      mgemm_k<<<dim3(4,384), 256, 0, stream>>>(Hb, Wot, bo + (size_t)wi*DM, Y1, X, nullptr, 256, 256, 1);
      // H2 = LN2(Y1) -> Hb
      ln_k<<<dim3(RB/4), 256, 0, stream>>>(Y1, Hb, ln2s + (size_t)wi*DM, ln2b + (size_t)wi*DM);
      // FFI = gelu(H2@W1 + b1) -> Qb..Kb (bf16, RB x 512)
      mgemm_k<<<dim3(8,384), 256, 0, stream>>>(Hb, W1t, b1 + (size_t)wi*512, Qb, nullptr, nullptr, 256, 512, 2);
      // X = 0.5*(X + Y1 + FFI@W2 + b2) (fp32, in place)
      mgemm_k<<<dim3(4,384), 256, 0, stream>>>(Qb, W2t, b2 + (size_t)wi*DM, X, X, Y1, 512, 256, 3);
    }
    zacc_k<<<dim3(RB/4), 256, 0, stream>>>(X, fw, fb, Zb, s);
  }

  out_k<<<dim3(BSZ), 256, 0, stream>>>(Zb, outw, outb, out);
}

// Round 6
// 11798.152 us; speedup vs baseline: 1.6456x; 1.4370x over previous
//
#include <hip/hip_runtime.h>
#include <hip/hip_bf16.h>
#include <math.h>

// ---- model dims ----
#define BSZ 32
#define SEQ 1536
#define DM 256
#define NH 8
#define DH 32
#define MF 110
#define NL 6
#define RB (BSZ*SEQ)          // rows per stream = 49152
#define NCH 12
#define CH (SEQ/NCH)          // 128 rows per attention chunk

#define NRM 0.4204482076268573f         // 32^-0.25
#define HALF_NRM2 0.08838834764831845f  // 0.5/sqrt(32)
#define RATIO 0.09534625892455922f      // 110^-0.5
#define PEPS 1e-4f

typedef unsigned short u16;
using short8v = __attribute__((ext_vector_type(8))) short;
using f32x4   = __attribute__((ext_vector_type(4))) float;

#define GLOAD_LDS16(g, l) __builtin_amdgcn_global_load_lds( \
    (const __attribute__((address_space(1))) void*)(g), \
    (__attribute__((address_space(3))) void*)(l), 16, 0, 0)

__device__ __forceinline__ float wredsum(float v){
  #pragma unroll
  for (int o=32;o;o>>=1) v += __shfl_xor(v,o);
  return v;
}
__device__ __forceinline__ u16 f2bf(float x){
  unsigned u = __float_as_uint(x);
  return (u16)((u + 0x7FFFu + ((u>>16)&1u)) >> 16);
}
__device__ __forceinline__ float b2f(u16 h){
  return __uint_as_float(((unsigned)h)<<16);
}

// ---------------- sentinel ----------------
__global__ __launch_bounds__(256) void sentinel_k(float* __restrict__ out, int n, float v)
{
  int i = blockIdx.x*256 + threadIdx.x;
  if (i < n) out[i] = v;
}

// ---------------- weight transpose+convert: src fp32 [L][K][N] -> dst bf16 [L][N][K] ----------------
__global__ __launch_bounds__(256) void wtrans_k(
    const float* __restrict__ src, u16* __restrict__ dst,
    int K, int N, size_t dstStride)
{
  int l = blockIdx.z;
  const float* s = src + (size_t)l*K*N;
  u16* d = dst + (size_t)l*dstStride;
  __shared__ float t[32][33];
  int k0 = blockIdx.y*32, n0 = blockIdx.x*32;
  int tx = threadIdx.x & 31, ty = threadIdx.x >> 5;   // 32 x 8
  #pragma unroll
  for (int i=0;i<32;i+=8) t[ty+i][tx] = s[(size_t)(k0+ty+i)*N + n0+tx];
  __syncthreads();
  #pragma unroll
  for (int i=0;i<32;i+=8) d[(size_t)(n0+ty+i)*K + k0+tx] = f2bf(t[tx][ty+i]);
}

// ---------------- embed: build X (fp32) for one stream ----------------
__global__ __launch_bounds__(256) void embed_k(
    const float* __restrict__ mag, const float* __restrict__ syn,
    const float* __restrict__ magT, const float* __restrict__ synT,
    const float* __restrict__ se, const float* __restrict__ seT,
    float* __restrict__ X, int s)
{
  int tid = threadIdx.x; int w = tid>>6; int lane = tid&63;
  int row = blockIdx.x*4 + w;
  int b = row / SEQ, t = row % SEQ;
  float val; const float* sep;
  if (!s) {
    int l = t / 192, c = t % 192;
    val = (c < 128) ? mag[((size_t)b*8 + l)*128 + c]
                    : syn[((size_t)b*8 + l)*64 + (c-128)];
    sep = se;
  } else {
    int r = t >> 3, l = t & 7;
    val = (r < 128) ? magT[((size_t)b*128 + r)*8 + l]
                    : synT[((size_t)b*64 + (r-128))*8 + l];
    sep = seT;
  }
  float4 e = *(const float4*)&sep[(size_t)t*DM + lane*4];
  float4 o = make_float4(val*e.x, val*e.y, val*e.z, val*e.w);
  *(float4*)&X[(size_t)row*DM + lane*4] = o;
}

// ---------------- LayerNorm: fp32 in -> bf16 out ----------------
__global__ __launch_bounds__(256) void ln_k(
    const float* __restrict__ in, u16* __restrict__ out,
    const float* __restrict__ sc, const float* __restrict__ sb)
{
  int tid=threadIdx.x, w=tid>>6, lane=tid&63;
  size_t row = (size_t)blockIdx.x*4 + w;
  const float4 v = *(const float4*)&in[row*DM + lane*4];
  float sum = v.x+v.y+v.z+v.w;
  sum = wredsum(sum);
  float mu = sum * (1.f/256.f);
  float dx=v.x-mu, dy=v.y-mu, dz=v.z-mu, dw=v.w-mu;
  float vs = dx*dx+dy*dy+dz*dz+dw*dw;
  vs = wredsum(vs);
  float rstd = rsqrtf(vs*(1.f/256.f) + 1e-5f);
  float4 s4 = *(const float4*)&sc[lane*4];
  float4 b4 = *(const float4*)&sb[lane*4];
  ushort4 o;
  o.x = f2bf(dx*rstd*s4.x+b4.x); o.y = f2bf(dy*rstd*s4.y+b4.y);
  o.z = f2bf(dz*rstd*s4.z+b4.z); o.w = f2bf(dw*rstd*s4.w+b4.w);
  *(ushort4*)&out[row*DM + lane*4] = o;
}

// ---------------- MFMA GEMM: C = epi(A@Wt^T + bias) ----------------
// A: [M,K] bf16 row-major. Wt: [N,K] bf16 row-major. Tile 128x64, 4 waves 2x2.
// EPI: 0 -> bf16 out; 1 -> f32 out (+R1); 2 -> bf16 out gelu; 3 -> f32 out 0.5*(R1+R2+.)
__global__ __launch_bounds__(256) void mgemm_k(
    const u16* __restrict__ A, const u16* __restrict__ Wt,
    const float* __restrict__ bias, void* __restrict__ Cout,
    const float* __restrict__ R1, const float* __restrict__ R2,
    int K, int N, int EPI)
{
  __shared__ u16 As[128*32];   // [row][k] linear, 64B rows
  __shared__ u16 Bs[64*32];    // [col][k] linear
  const int tid = threadIdx.x;
  const int lane = tid & 63, w = tid >> 6;
  const int wr = w >> 1, wc = w & 1;
  const int r0 = blockIdx.y*128, c0 = blockIdx.x*64;

  f32x4 acc[4][2];
  #pragma unroll
  for (int m=0;m<4;m++){
    #pragma unroll
    for (int n=0;n<2;n++) acc[m][n] = (f32x4){0.f,0.f,0.f,0.f};
  }
  const int lr = lane>>2;          // 0..15 row-in-chunk
  const int lk = (lane&3)*8;       // k offset
  for (int k0 = 0; k0 < K; k0 += 32){
    GLOAD_LDS16(&A[(size_t)(r0 + w*32      + lr)*K + k0 + lk], &As[(w*32     )*32]);
    GLOAD_LDS16(&A[(size_t)(r0 + w*32 + 16 + lr)*K + k0 + lk], &As[(w*32 + 16)*32]);
    GLOAD_LDS16(&Wt[(size_t)(c0 + w*16 + lr)*K + k0 + lk], &Bs[(w*16)*32]);
    __syncthreads();
    short8v a[4], bq[2];
    #pragma unroll
    for (int m=0;m<4;m++)
      a[m] = *(const short8v*)&As[(wr*64 + m*16 + (lane&15))*32 + (lane>>4)*8];
    #pragma unroll
    for (int n=0;n<2;n++)
      bq[n] = *(const short8v*)&Bs[(wc*32 + n*16 + (lane&15))*32 + (lane>>4)*8];
    #pragma unroll
    for (int m=0;m<4;m++){
      #pragma unroll
      for (int n=0;n<2;n++)
        acc[m][n] = __builtin_amdgcn_mfma_f32_16x16x32_bf16(a[m], bq[n], acc[m][n], 0,0,0);
    }
    __syncthreads();
  }
  const int cb = c0 + wc*32 + (lane&15);
  const int rb = r0 + wr*64 + (lane>>4)*4;
  #pragma unroll
  for (int m=0;m<4;m++){
    #pragma unroll
    for (int n=0;n<2;n++){
      int c = cb + n*16;
      float bb = bias[c];
      #pragma unroll
      for (int i=0;i<4;i++){
        int r = rb + m*16 + i;
        size_t off = (size_t)r*N + c;
        float v = acc[m][n][i] + bb;
        if (EPI == 0) {
          ((u16*)Cout)[off] = f2bf(v);
        } else if (EPI == 1) {
          ((float*)Cout)[off] = v + R1[off];
        } else if (EPI == 2) {
          v = 0.5f*v*(1.f+erff(v*0.70710678118654752f));
          ((u16*)Cout)[off] = f2bf(v);
        } else {
          ((float*)Cout)[off] = 0.5f*(R1[off] + R2[off] + v);
        }
      }
    }
  }
}

// ---------------- Performer: chunk max of K-dot per (b,h,chunk) ----------------
__global__ __launch_bounds__(128) void ctxmax_k(
    const u16* __restrict__ Kin, const float* __restrict__ proj,
    float* __restrict__ pmax)
{
  int h = blockIdx.x, b = blockIdx.y, ch = blockIdx.z;
  int tid = threadIdx.x;
  __shared__ float Ks[CH][33];
  __shared__ float red[128];
  const u16* Kb = Kin + ((size_t)b*SEQ + ch*CH)*DM + h*32;
  #pragma unroll
  for (int i=0;i<4;i++){
    int f = tid + i*128;            // short8 units: CH*4
    int r = f >> 2, c8 = (f & 3)*8;
    short8v v = *(const short8v*)&Kb[(size_t)r*DM + c8];
    #pragma unroll
    for (int j=0;j<8;j++) Ks[r][c8+j] = b2f((u16)v[j]);
  }
  __syncthreads();
  float mx = -1e30f;
  if (tid < MF){
    float pr[32];
    #pragma unroll
    for (int d=0;d<32;d++) pr[d] = proj[tid*32+d];
    for (int r=0;r<CH;r++){
      float dot=0.f;
      #pragma unroll
      for (int d=0;d<32;d++) dot += Ks[r][d]*pr[d];
      mx = fmaxf(mx, dot);
    }
  }
  red[tid] = mx;
  __syncthreads();
  for (int st=64; st; st>>=1){
    if (tid<st) red[tid] = fmaxf(red[tid], red[tid+st]);
    __syncthreads();
  }
  if (tid==0) pmax[(size_t)(b*NH+h)*NCH + ch] = red[0];
}

// ---------------- Performer: chunk ctx/ksum partials (no atomics) ----------------
// part layout: [NCH][256bh][MF][36]  (32 ctx + ksum at [32] + 3 pad)
__global__ __launch_bounds__(128) void ctxacc_k(
    const u16* __restrict__ Kin, const u16* __restrict__ Vin,
    const float* __restrict__ proj, const float* __restrict__ pmax,
    float* __restrict__ part)
{
  int h = blockIdx.x, b = blockIdx.y, ch = blockIdx.z;
  int tid = threadIdx.x;
  int bh = b*NH + h;
  __shared__ float Ks[CH][33];
  __shared__ float Vs[CH][33];
  __shared__ float diag_s[CH];
  const u16* Kb = Kin + ((size_t)b*SEQ + ch*CH)*DM + h*32;
  const u16* Vb = Vin + ((size_t)b*SEQ + ch*CH)*DM + h*32;
  #pragma unroll
  for (int i=0;i<4;i++){
    int f = tid + i*128;
    int r = f >> 2, c8 = (f & 3)*8;
    short8v vk = *(const short8v*)&Kb[(size_t)r*DM + c8];
    short8v vv = *(const short8v*)&Vb[(size_t)r*DM + c8];
    #pragma unroll
    for (int j=0;j<8;j++){ Ks[r][c8+j] = b2f((u16)vk[j]); Vs[r][c8+j] = b2f((u16)vv[j]); }
  }
  __syncthreads();
  {
    float ss=0.f;
    #pragma unroll
    for (int d=0;d<32;d++){ float k=Ks[tid][d]; ss += k*k; }
    diag_s[tid] = HALF_NRM2 * ss;
  }
  float gm = -1e30f;
  #pragma unroll
  for (int c=0;c<NCH;c++) gm = fmaxf(gm, pmax[(size_t)bh*NCH + c]);
  float stab = NRM * gm;
  __syncthreads();
  if (tid < MF){
    float pr[32], cm[32];
    #pragma unroll
    for (int d=0;d<32;d++){ pr[d] = proj[tid*32+d]; cm[d]=0.f; }
    float ks = 0.f;
    for (int r=0;r<CH;r++){
      float dot=0.f;
      #pragma unroll
      for (int d=0;d<32;d++) dot += Ks[r][d]*pr[d];
      float phi = RATIO * (__expf(NRM*dot - diag_s[r] - stab) + PEPS);
      ks += phi;
      #pragma unroll
      for (int d=0;d<32;d++) cm[d] += phi * Vs[r][d];
    }
    float* pp = part + (((size_t)ch*256 + bh)*MF + tid)*36;
    #pragma unroll
    for (int q=0;q<8;q++)
      *(float4*)&pp[q*4] = make_float4(cm[q*4],cm[q*4+1],cm[q*4+2],cm[q*4+3]);
    pp[32] = ks;
  }
}

// ---------------- reduce chunk partials -> ctx/ksum ----------------
__global__ __launch_bounds__(256) void ctxred_k(
    const float* __restrict__ part, float* __restrict__ ctxg, float* __restrict__ ksumg)
{
  int t = blockIdx.x*256 + threadIdx.x;   // t in [0, 256*MF*36)
  int d = t % 36;
  if (d >= 33) return;
  float s = 0.f;
  #pragma unroll
  for (int ch=0; ch<NCH; ch++) s += part[(size_t)ch*256*MF*36 + t];
  int bhm = t / 36;
  if (d < 32) ctxg[(size_t)bhm*32 + d] = s;
  else        ksumg[bhm] = s;
}

// ---------------- Performer: O = (phi(q)@ctx)/denom per row (bf16 Q in, bf16 O out) ----------------
__global__ __launch_bounds__(256) void o_k(
    const u16* __restrict__ Qin, const float* __restrict__ proj,
    const float* __restrict__ ctxg, const float* __restrict__ ksumg,
    u16* __restrict__ Og)
{
  int n0 = blockIdx.x*64, h = blockIdx.y, b = blockIdx.z;
  int tid=threadIdx.x, w=tid>>6, lane=tid&63;
  __shared__ float proj_s[MF][33];
  __shared__ float ctx_s[MF][33];
  __shared__ float ksum_s[MF];
  __shared__ float qs[4][32];
  __shared__ float phi_s[4][112];
  for (int idx=tid; idx<MF*32; idx+=256){
    proj_s[idx>>5][idx&31] = proj[idx];
    ctx_s[idx>>5][idx&31] = ctxg[(size_t)(b*NH+h)*MF*32 + idx];
  }
  for (int idx=tid; idx<MF; idx+=256) ksum_s[idx] = ksumg[(size_t)(b*NH+h)*MF + idx];
  __syncthreads();
  const int m_a = lane;
  const int m_b = lane + 64;
  const bool hb = (m_b < MF);
  const int half = lane>>5, d2 = lane&31;
  for (int it=0; it<16; it++){
    int n = n0 + it*4 + w;
    size_t qoff = ((size_t)b*SEQ + n)*DM + h*32;
    if (lane < 32) qs[w][lane] = b2f(Qin[qoff + lane]);
    __syncthreads();
    float ss=0.f;
    #pragma unroll
    for (int d=0;d<32;d++){ float q=qs[w][d]; ss += q*q; }
    float diag = HALF_NRM2 * ss;
    float xa=0.f, xb=0.f;
    #pragma unroll
    for (int d=0;d<32;d++){
      float q = qs[w][d];
      xa += q * proj_s[m_a][d];
      if (hb) xb += q * proj_s[m_b][d];
    }
    xa *= NRM; xb *= NRM;
    float mxv = fmaxf(xa, hb ? xb : -1e30f);
    #pragma unroll
    for (int o=32;o;o>>=1) mxv = fmaxf(mxv, __shfl_xor(mxv,o));
    float pa = RATIO*(__expf(xa - diag - mxv) + PEPS);
    float pb = hb ? RATIO*(__expf(xb - diag - mxv) + PEPS) : 0.f;
    phi_s[w][m_a] = pa;
    if (hb) phi_s[w][m_b] = pb;
    float dn = pa * ksum_s[m_a] + (hb ? pb * ksum_s[m_b] : 0.f);
    dn = wredsum(dn);
    float rden = 1.f / dn;
    float acc = 0.f;
    for (int mm=0; mm<55; mm++){
      int m = half*55 + mm;
      acc += phi_s[w][m] * ctx_s[m][d2];
    }
    acc += __shfl_xor(acc, 32);
    if (lane < 32) Og[qoff + lane] = f2bf(acc * rden);
    __syncthreads();
  }
}

// ---------------- z accumulation ----------------
__global__ __launch_bounds__(256) void zacc_k(
    const float* __restrict__ X, const float* __restrict__ fw,
    const float* __restrict__ fb, float* __restrict__ Z, int mode)
{
  int tid=threadIdx.x, w=tid>>6, lane=tid&63;
  int row = blockIdx.x*4 + w;
  int b = row/SEQ, t = row%SEQ;
  int tt = t;
  if (mode == 1) {
    int l = t/192, r = t%192;
    tt = r*8 + l;
  }
  const float4 x0 = *(const float4*)&X[((size_t)b*SEQ + tt)*DM + lane*4];
  const float4 f4 = *(const float4*)&fw[lane*4];
  float ssum = x0.x*f4.x + x0.y*f4.y + x0.z*f4.z + x0.w*f4.w;
  ssum = wredsum(ssum);
  if (lane==0) {
    if (mode == 0) Z[row] = ssum + fb[0];
    else           Z[row] += ssum;
  }
}

// ---------------- out = z @ out_w + out_b ----------------
__global__ __launch_bounds__(256) void out_k(
    const float* __restrict__ Z, const float* __restrict__ outw,
    const float* __restrict__ outb, float* __restrict__ out)
{
  int b = blockIdx.x; int tid = threadIdx.x;
  float4 acc = make_float4(0.f,0.f,0.f,0.f);
  const float* zrow = Z + (size_t)b*SEQ;
  for (int t=0;t<SEQ;t++){
    float zv = zrow[t];
    float4 wv = *(const float4*)&outw[(size_t)t*1024 + tid*4];
    acc.x += zv*wv.x; acc.y += zv*wv.y; acc.z += zv*wv.z; acc.w += zv*wv.w;
  }
  float4 ob = *(const float4*)&outb[tid*4];
  float4 o = make_float4(acc.x+ob.x, acc.y+ob.y, acc.z+ob.z, acc.w+ob.w);
  *(float4*)&out[(size_t)b*1024 + tid*4] = o;
}

extern "C" void kernel_launch(void* const* d_in, const int* in_sizes, int n_in,
                              void* d_out, int out_size, void* d_ws, size_t ws_size,
                              hipStream_t stream) {
  (void)in_sizes; (void)n_in;
  const float* mag  = (const float*)d_in[0];
  const float* syn  = (const float*)d_in[1];
  const float* magT = (const float*)d_in[2];
  const float* synT = (const float*)d_in[3];
  const float* se   = (const float*)d_in[4];
  const float* seT  = (const float*)d_in[5];
  const float* ln1s = (const float*)d_in[6];
  const float* ln1b = (const float*)d_in[7];
  const float* Wq   = (const float*)d_in[8];
  const float* bq   = (const float*)d_in[9];
  const float* Wk   = (const float*)d_in[10];
  const float* bk   = (const float*)d_in[11];
  const float* Wv   = (const float*)d_in[12];
  const float* bv   = (const float*)d_in[13];
  const float* Wo   = (const float*)d_in[14];
  const float* bo   = (const float*)d_in[15];
  const float* proj = (const float*)d_in[16];
  const float* ln2s = (const float*)d_in[17];
  const float* ln2b = (const float*)d_in[18];
  const float* W1   = (const float*)d_in[19];
  const float* b1   = (const float*)d_in[20];
  const float* W2   = (const float*)d_in[21];
  const float* b2   = (const float*)d_in[22];
  const float* fw   = (const float*)d_in[23];
  const float* fb   = (const float*)d_in[24];
  const float* outw = (const float*)d_in[25];
  const float* outb = (const float*)d_in[26];
  float* out = (float*)d_out;

  // ---- workspace layout (bytes) ----
  char* base = (char*)d_ws;
  const size_t PANEL = (size_t)RB*DM;               // elements
  size_t off = 0;
  float* X   = (float*)(base + off); off += PANEL*4;
  float* Y1  = (float*)(base + off); off += PANEL*4;   // also PART buffer during attention
  u16*  Hb   = (u16*)(base + off);   off += PANEL*2;
  u16*  Qb   = (u16*)(base + off);   off += PANEL*2;   // FFI = Qb spanning Qb+Kb (RB x 512)
  u16*  Kb   = (u16*)(base + off);   off += PANEL*2;
  u16*  Vb   = (u16*)(base + off);   off += PANEL*2;
  u16*  Wts  = (u16*)(base + off);   off += (size_t)12*524288*2;
  float* CTXb= (float*)(base + off); off += (size_t)256*MF*32*4;
  float* KSb = (float*)(base + off); off += (size_t)256*MF*4;
  float* PMb = (float*)(base + off); off += (size_t)256*NCH*4;
  float* Zb  = (float*)(base + off); off += (size_t)BSZ*SEQ*4;
  if (ws_size < off) {
    float v = 100000.0f + (float)(ws_size >> 20);
    sentinel_k<<<dim3((out_size+255)/256), 256, 0, stream>>>(out, out_size, v);
    return;
  }
  float* PARTb = Y1;   // [NCH][256][MF][36] = 48.6 MB <= 50.3 MB (Y1 dead during attention)
  const size_t WST = 524288;

  // ---- transpose+convert all weights (both streams, 12 layers) ----
  wtrans_k<<<dim3(8,8,12),  256, 0, stream>>>(Wq, Wts + 0,      256, 256, WST);
  wtrans_k<<<dim3(8,8,12),  256, 0, stream>>>(Wk, Wts + 65536,  256, 256, WST);
  wtrans_k<<<dim3(8,8,12),  256, 0, stream>>>(Wv, Wts + 131072, 256, 256, WST);
  wtrans_k<<<dim3(8,8,12),  256, 0, stream>>>(Wo, Wts + 196608, 256, 256, WST);
  wtrans_k<<<dim3(16,8,12), 256, 0, stream>>>(W1, Wts + 262144, 256, 512, WST);
  wtrans_k<<<dim3(8,16,12), 256, 0, stream>>>(W2, Wts + 393216, 512, 256, WST);

  for (int s=0; s<2; s++){
    embed_k<<<dim3(RB/4), 256, 0, stream>>>(mag, syn, magT, synT, se, seT, X, s);
    for (int l=0; l<NL; l++){
      int wi = s*NL + l;
      const u16* Wqt = Wts + (size_t)wi*WST;
      const u16* Wkt = Wqt + 65536;
      const u16* Wvt = Wqt + 131072;
      const u16* Wot = Wqt + 196608;
      const u16* W1t = Wqt + 262144;
      const u16* W2t = Wqt + 393216;
      const float* pproj = proj + (size_t)wi*MF*DH;

      // H = LN1(X) -> Hb (bf16)
      ln_k<<<dim3(RB/4), 256, 0, stream>>>(X, Hb, ln1s + (size_t)wi*DM, ln1b + (size_t)wi*DM);
      // Q,K,V
      mgemm_k<<<dim3(4,384), 256, 0, stream>>>(Hb, Wqt, bq + (size_t)wi*DM, Qb, nullptr, nullptr, 256, 256, 0);
      mgemm_k<<<dim3(4,384), 256, 0, stream>>>(Hb, Wkt, bk + (size_t)wi*DM, Kb, nullptr, nullptr, 256, 256, 0);
      mgemm_k<<<dim3(4,384), 256, 0, stream>>>(Hb, Wvt, bv + (size_t)wi*DM, Vb, nullptr, nullptr, 256, 256, 0);
      // attention ctx/ksum (chunk-parallel, no atomics)
      ctxmax_k<<<dim3(NH,BSZ,NCH), 128, 0, stream>>>(Kb, pproj, PMb);
      ctxacc_k<<<dim3(NH,BSZ,NCH), 128, 0, stream>>>(Kb, Vb, pproj, PMb, PARTb);
      ctxred_k<<<dim3(MF*36), 256, 0, stream>>>(PARTb, CTXb, KSb);
      // O -> Hb (bf16, H consumed)
      o_k<<<dim3(SEQ/64, NH, BSZ), 256, 0, stream>>>(Qb, pproj, CTXb, KSb, Hb);
      // Y1 = X + O@Wo + bo (fp32)  (overwrites PART space - PART consumed)
      mgemm_k<<<dim3(4,384), 256, 0, stream>>>(Hb, Wot, bo + (size_t)wi*DM, Y1, X, nullptr, 256, 256, 1);
      // H2 = LN2(Y1) -> Hb
      ln_k<<<dim3(RB/4), 256, 0, stream>>>(Y1, Hb, ln2s + (size_t)wi*DM, ln2b + (size_t)wi*DM);
      // FFI = gelu(H2@W1 + b1) -> Qb..Kb (bf16, RB x 512)
      mgemm_k<<<dim3(8,384), 256, 0, stream>>>(Hb, W1t, b1 + (size_t)wi*512, Qb, nullptr, nullptr, 256, 512, 2);
      // X = 0.5*(X + Y1 + FFI@W2 + b2) (fp32, in place)
      mgemm_k<<<dim3(4,384), 256, 0, stream>>>(Qb, W2t, b2 + (size_t)wi*DM, X, X, Y1, 512, 256, 3);
    }
    zacc_k<<<dim3(RB/4), 256, 0, stream>>>(X, fw, fb, Zb, s);
  }

  out_k<<<dim3(BSZ), 256, 0, stream>>>(Zb, outw, outb, out);
}

// Round 7
// 9706.008 us; speedup vs baseline: 2.0003x; 1.2156x over previous
//
#include <hip/hip_runtime.h>
#include <hip/hip_bf16.h>
#include <math.h>

// ---- model dims ----
#define BSZ 32
#define SEQ 1536
#define DM 256
#define NH 8
#define DH 32
#define MF 110
#define NL 6
#define RB (BSZ*SEQ)          // rows per stream = 49152
#define NCH 12
#define CH (SEQ/NCH)          // 128 rows per attention chunk

#define NRM 0.4204482076268573f         // 32^-0.25
#define HALF_NRM2 0.08838834764831845f  // 0.5/sqrt(32)
#define RATIO 0.09534625892455922f      // 110^-0.5
#define PEPS 1e-4f

typedef unsigned short u16;
using short8v = __attribute__((ext_vector_type(8))) short;
using f32x4   = __attribute__((ext_vector_type(4))) float;

#define GLOAD_LDS16(g, l) __builtin_amdgcn_global_load_lds( \
    (const __attribute__((address_space(1))) void*)(g), \
    (__attribute__((address_space(3))) void*)(l), 16, 0, 0)

__device__ __forceinline__ float wredsum(float v){
  #pragma unroll
  for (int o=32;o;o>>=1) v += __shfl_xor(v,o);
  return v;
}
__device__ __forceinline__ float wredmax(float v){
  #pragma unroll
  for (int o=32;o;o>>=1) v = fmaxf(v, __shfl_xor(v,o));
  return v;
}
__device__ __forceinline__ u16 f2bf(float x){
  unsigned u = __float_as_uint(x);
  return (u16)((u + 0x7FFFu + ((u>>16)&1u)) >> 16);
}
__device__ __forceinline__ float b2f(u16 h){
  return __uint_as_float(((unsigned)h)<<16);
}

// ---------------- sentinel ----------------
__global__ __launch_bounds__(256) void sentinel_k(float* __restrict__ out, int n, float v)
{
  int i = blockIdx.x*256 + threadIdx.x;
  if (i < n) out[i] = v;
}

// ---------------- weight transpose+convert: src fp32 [L][K][N] -> dst bf16 [L][N][K] ----------------
__global__ __launch_bounds__(256) void wtrans_k(
    const float* __restrict__ src, u16* __restrict__ dst,
    int K, int N, size_t dstStride)
{
  int l = blockIdx.z;
  const float* s = src + (size_t)l*K*N;
  u16* d = dst + (size_t)l*dstStride;
  __shared__ float t[32][33];
  int k0 = blockIdx.y*32, n0 = blockIdx.x*32;
  int tx = threadIdx.x & 31, ty = threadIdx.x >> 5;   // 32 x 8
  #pragma unroll
  for (int i=0;i<32;i+=8) t[ty+i][tx] = s[(size_t)(k0+ty+i)*N + n0+tx];
  __syncthreads();
  #pragma unroll
  for (int i=0;i<32;i+=8) d[(size_t)(n0+ty+i)*K + k0+tx] = f2bf(t[tx][ty+i]);
}

// ---------------- embed: build X (fp32) for one stream ----------------
__global__ __launch_bounds__(256) void embed_k(
    const float* __restrict__ mag, const float* __restrict__ syn,
    const float* __restrict__ magT, const float* __restrict__ synT,
    const float* __restrict__ se, const float* __restrict__ seT,
    float* __restrict__ X, int s)
{
  int tid = threadIdx.x; int w = tid>>6; int lane = tid&63;
  int row = blockIdx.x*4 + w;
  int b = row / SEQ, t = row % SEQ;
  float val; const float* sep;
  if (!s) {
    int l = t / 192, c = t % 192;
    val = (c < 128) ? mag[((size_t)b*8 + l)*128 + c]
                    : syn[((size_t)b*8 + l)*64 + (c-128)];
    sep = se;
  } else {
    int r = t >> 3, l = t & 7;
    val = (r < 128) ? magT[((size_t)b*128 + r)*8 + l]
                    : synT[((size_t)b*64 + (r-128))*8 + l];
    sep = seT;
  }
  float4 e = *(const float4*)&sep[(size_t)t*DM + lane*4];
  float4 o = make_float4(val*e.x, val*e.y, val*e.z, val*e.w);
  *(float4*)&X[(size_t)row*DM + lane*4] = o;
}

// ---------------- LayerNorm: fp32 in -> bf16 out ----------------
__global__ __launch_bounds__(256) void ln_k(
    const float* __restrict__ in, u16* __restrict__ out,
    const float* __restrict__ sc, const float* __restrict__ sb)
{
  int tid=threadIdx.x, w=tid>>6, lane=tid&63;
  size_t row = (size_t)blockIdx.x*4 + w;
  const float4 v = *(const float4*)&in[row*DM + lane*4];
  float sum = v.x+v.y+v.z+v.w;
  sum = wredsum(sum);
  float mu = sum * (1.f/256.f);
  float dx=v.x-mu, dy=v.y-mu, dz=v.z-mu, dw=v.w-mu;
  float vs = dx*dx+dy*dy+dz*dz+dw*dw;
  vs = wredsum(vs);
  float rstd = rsqrtf(vs*(1.f/256.f) + 1e-5f);
  float4 s4 = *(const float4*)&sc[lane*4];
  float4 b4 = *(const float4*)&sb[lane*4];
  ushort4 o;
  o.x = f2bf(dx*rstd*s4.x+b4.x); o.y = f2bf(dy*rstd*s4.y+b4.y);
  o.z = f2bf(dz*rstd*s4.z+b4.z); o.w = f2bf(dw*rstd*s4.w+b4.w);
  *(ushort4*)&out[row*DM + lane*4] = o;
}

// ---------------- MFMA GEMM: C = epi(A@Wt^T + bias) ----------------
__global__ __launch_bounds__(256) void mgemm_k(
    const u16* __restrict__ A, const u16* __restrict__ Wt,
    const float* __restrict__ bias, void* __restrict__ Cout,
    const float* __restrict__ R1, const float* __restrict__ R2,
    int K, int N, int EPI)
{
  __shared__ u16 As[128*32];   // [row][k] linear
  __shared__ u16 Bs[64*32];    // [col][k] linear
  const int tid = threadIdx.x;
  const int lane = tid & 63, w = tid >> 6;
  const int wr = w >> 1, wc = w & 1;
  const int r0 = blockIdx.y*128, c0 = blockIdx.x*64;

  f32x4 acc[4][2];
  #pragma unroll
  for (int m=0;m<4;m++){
    #pragma unroll
    for (int n=0;n<2;n++) acc[m][n] = (f32x4){0.f,0.f,0.f,0.f};
  }
  const int lr = lane>>2;
  const int lk = (lane&3)*8;
  for (int k0 = 0; k0 < K; k0 += 32){
    GLOAD_LDS16(&A[(size_t)(r0 + w*32      + lr)*K + k0 + lk], &As[(w*32     )*32]);
    GLOAD_LDS16(&A[(size_t)(r0 + w*32 + 16 + lr)*K + k0 + lk], &As[(w*32 + 16)*32]);
    GLOAD_LDS16(&Wt[(size_t)(c0 + w*16 + lr)*K + k0 + lk], &Bs[(w*16)*32]);
    __syncthreads();
    short8v a[4], bq[2];
    #pragma unroll
    for (int m=0;m<4;m++)
      a[m] = *(const short8v*)&As[(wr*64 + m*16 + (lane&15))*32 + (lane>>4)*8];
    #pragma unroll
    for (int n=0;n<2;n++)
      bq[n] = *(const short8v*)&Bs[(wc*32 + n*16 + (lane&15))*32 + (lane>>4)*8];
    #pragma unroll
    for (int m=0;m<4;m++){
      #pragma unroll
      for (int n=0;n<2;n++)
        acc[m][n] = __builtin_amdgcn_mfma_f32_16x16x32_bf16(a[m], bq[n], acc[m][n], 0,0,0);
    }
    __syncthreads();
  }
  const int cb = c0 + wc*32 + (lane&15);
  const int rb = r0 + wr*64 + (lane>>4)*4;
  #pragma unroll
  for (int m=0;m<4;m++){
    #pragma unroll
    for (int n=0;n<2;n++){
      int c = cb + n*16;
      float bb = bias[c];
      #pragma unroll
      for (int i=0;i<4;i++){
        int r = rb + m*16 + i;
        size_t off = (size_t)r*N + c;
        float v = acc[m][n][i] + bb;
        if (EPI == 0) {
          ((u16*)Cout)[off] = f2bf(v);
        } else if (EPI == 1) {
          ((float*)Cout)[off] = v + R1[off];
        } else if (EPI == 2) {
          v = 0.5f*v*(1.f+erff(v*0.70710678118654752f));
          ((u16*)Cout)[off] = f2bf(v);
        } else {
          ((float*)Cout)[off] = 0.5f*(R1[off] + R2[off] + v);
        }
      }
    }
  }
}

// ---------------- Performer: chunk max of K-dot per (b,h,chunk) ----------------
__global__ __launch_bounds__(128) void ctxmax_k(
    const u16* __restrict__ Kin, const float* __restrict__ proj,
    float* __restrict__ pmax)
{
  int h = blockIdx.x, b = blockIdx.y, ch = blockIdx.z;
  int tid = threadIdx.x;
  __shared__ __align__(16) float Ks[CH][36];
  __shared__ float red[128];
  const u16* Kb = Kin + ((size_t)b*SEQ + ch*CH)*DM + h*32;
  #pragma unroll
  for (int i=0;i<8;i++){
    int f = tid + i*128;            // float4 slot 0..1023
    int r = f >> 3, c4 = (f & 7)*4;
    ushort4 v = *(const ushort4*)&Kb[(size_t)r*DM + c4];
    *(float4*)&Ks[r][c4] = make_float4(b2f(v.x), b2f(v.y), b2f(v.z), b2f(v.w));
  }
  __syncthreads();
  float mx = -1e30f;
  if (tid < MF){
    float pr[32];
    #pragma unroll
    for (int d=0;d<32;d++) pr[d] = proj[tid*32+d];
    for (int r=0;r<CH;r++){
      float dot=0.f;
      #pragma unroll
      for (int dq=0;dq<8;dq++){
        float4 kk = *(const float4*)&Ks[r][dq*4];
        dot += kk.x*pr[dq*4] + kk.y*pr[dq*4+1] + kk.z*pr[dq*4+2] + kk.w*pr[dq*4+3];
      }
      mx = fmaxf(mx, dot);
    }
  }
  red[tid] = mx;
  __syncthreads();
  for (int st=64; st; st>>=1){
    if (tid<st) red[tid] = fmaxf(red[tid], red[tid+st]);
    __syncthreads();
  }
  if (tid==0) pmax[(size_t)(b*NH+h)*NCH + ch] = red[0];
}

// ---------------- Performer: chunk ctx/ksum partials (no atomics) ----------------
// part layout: [NCH][256bh][MF][36]  (32 ctx + ksum at [32] + 3 pad)
__global__ __launch_bounds__(128) void ctxacc_k(
    const u16* __restrict__ Kin, const u16* __restrict__ Vin,
    const float* __restrict__ proj, const float* __restrict__ pmax,
    float* __restrict__ part)
{
  int h = blockIdx.x, b = blockIdx.y, ch = blockIdx.z;
  int tid = threadIdx.x;
  int bh = b*NH + h;
  __shared__ __align__(16) float Ks[CH][36];
  __shared__ __align__(16) float Vs[CH][36];
  __shared__ float diag_s[CH];
  const u16* Kb = Kin + ((size_t)b*SEQ + ch*CH)*DM + h*32;
  const u16* Vb = Vin + ((size_t)b*SEQ + ch*CH)*DM + h*32;
  #pragma unroll
  for (int i=0;i<8;i++){
    int f = tid + i*128;
    int r = f >> 3, c4 = (f & 7)*4;
    ushort4 vk = *(const ushort4*)&Kb[(size_t)r*DM + c4];
    ushort4 vv = *(const ushort4*)&Vb[(size_t)r*DM + c4];
    *(float4*)&Ks[r][c4] = make_float4(b2f(vk.x), b2f(vk.y), b2f(vk.z), b2f(vk.w));
    *(float4*)&Vs[r][c4] = make_float4(b2f(vv.x), b2f(vv.y), b2f(vv.z), b2f(vv.w));
  }
  __syncthreads();
  {
    float ss=0.f;
    #pragma unroll
    for (int dq=0;dq<8;dq++){
      float4 kk = *(const float4*)&Ks[tid][dq*4];
      ss += kk.x*kk.x + kk.y*kk.y + kk.z*kk.z + kk.w*kk.w;
    }
    diag_s[tid] = HALF_NRM2 * ss;
  }
  float gm = -1e30f;
  #pragma unroll
  for (int c=0;c<NCH;c++) gm = fmaxf(gm, pmax[(size_t)bh*NCH + c]);
  float stab = NRM * gm;
  __syncthreads();
  if (tid < MF){
    float pr[32], cm[32];
    #pragma unroll
    for (int d=0;d<32;d++){ pr[d] = proj[tid*32+d]; cm[d]=0.f; }
    float ks = 0.f;
    for (int r=0;r<CH;r++){
      float dot=0.f;
      #pragma unroll
      for (int dq=0;dq<8;dq++){
        float4 kk = *(const float4*)&Ks[r][dq*4];
        dot += kk.x*pr[dq*4] + kk.y*pr[dq*4+1] + kk.z*pr[dq*4+2] + kk.w*pr[dq*4+3];
      }
      float phi = RATIO * (__expf(NRM*dot - diag_s[r] - stab) + PEPS);
      ks += phi;
      #pragma unroll
      for (int dq=0;dq<8;dq++){
        float4 vv = *(const float4*)&Vs[r][dq*4];
        cm[dq*4]   += phi * vv.x; cm[dq*4+1] += phi * vv.y;
        cm[dq*4+2] += phi * vv.z; cm[dq*4+3] += phi * vv.w;
      }
    }
    float* pp = part + (((size_t)ch*256 + bh)*MF + tid)*36;
    #pragma unroll
    for (int q=0;q<8;q++)
      *(float4*)&pp[q*4] = make_float4(cm[q*4],cm[q*4+1],cm[q*4+2],cm[q*4+3]);
    pp[32] = ks;
  }
}

// ---------------- reduce chunk partials -> ctx/ksum ----------------
__global__ __launch_bounds__(256) void ctxred_k(
    const float* __restrict__ part, float* __restrict__ ctxg, float* __restrict__ ksumg)
{
  int t = blockIdx.x*256 + threadIdx.x;   // t in [0, 256*MF*36)
  int d = t % 36;
  if (d >= 33) return;
  float s = 0.f;
  #pragma unroll
  for (int ch=0; ch<NCH; ch++) s += part[(size_t)ch*256*MF*36 + t];
  int bhm = t / 36;
  if (d < 32) ctxg[(size_t)bhm*32 + d] = s;
  else        ksumg[bhm] = s;
}

// ---------------- Performer O: register-hoisted, per-wave independent ----------------
// grid (SEQ/128, NH, BSZ), 256 threads = 4 waves, each wave 32 rows, no block syncs.
__global__ __launch_bounds__(256) void o_k(
    const u16* __restrict__ Qin, const float* __restrict__ proj,
    const float* __restrict__ ctxg, const float* __restrict__ ksumg,
    u16* __restrict__ Og)
{
  const int n0 = blockIdx.x*128, h = blockIdx.y, b = blockIdx.z;
  const int tid = threadIdx.x, wv = tid>>6, lane = tid&63;
  const int bh = b*NH + h;
  __shared__ __align__(16) float phi4[4][112];

  const int m_a = lane;               // < 110 always
  const int m_b = lane + 64;
  const bool hb = (m_b < MF);
  const int d2 = lane & 31, half = lane >> 5;

  // hoist proj rows (NRM-prescaled), ctx column, ksum scalars into registers
  float pra[32], prb[32];
  #pragma unroll
  for (int d=0; d<32; d++){
    pra[d] = NRM * proj[m_a*32 + d];
    prb[d] = hb ? NRM * proj[m_b*32 + d] : 0.f;
  }
  float ctxc[56];
  #pragma unroll
  for (int j=0; j<56; j++){
    int m = half*56 + j;
    ctxc[j] = (m < MF) ? ctxg[((size_t)bh*MF + m)*32 + d2] : 0.f;
  }
  const float ksa = ksumg[(size_t)bh*MF + m_a];
  const float ksb = hb ? ksumg[(size_t)bh*MF + m_b] : 0.f;
  // zero the phi tail once (m=110,111 never written)
  if (lane < 2) phi4[wv][110+lane] = 0.f;

  for (int it=0; it<32; it++){
    const int n = n0 + wv*32 + it;
    const size_t qoff = ((size_t)b*SEQ + n)*DM + h*32;
    const short8v* qp = (const short8v*)&Qin[qoff];   // wave-uniform address
    short8v q0 = qp[0], q1 = qp[1], q2 = qp[2], q3 = qp[3];
    float xa = 0.f, xb = 0.f, ss = 0.f;
    #pragma unroll
    for (int j=0; j<8; j++){
      float qf = b2f((u16)q0[j]);
      xa += qf*pra[j]; xb += qf*prb[j]; ss += qf*qf;
    }
    #pragma unroll
    for (int j=0; j<8; j++){
      float qf = b2f((u16)q1[j]);
      xa += qf*pra[8+j]; xb += qf*prb[8+j]; ss += qf*qf;
    }
    #pragma unroll
    for (int j=0; j<8; j++){
      float qf = b2f((u16)q2[j]);
      xa += qf*pra[16+j]; xb += qf*prb[16+j]; ss += qf*qf;
    }
    #pragma unroll
    for (int j=0; j<8; j++){
      float qf = b2f((u16)q3[j]);
      xa += qf*pra[24+j]; xb += qf*prb[24+j]; ss += qf*qf;
    }
    const float diag = HALF_NRM2 * ss;
    float mxv = hb ? fmaxf(xa, xb) : xa;
    mxv = wredmax(mxv);
    const float pa = RATIO*(__expf(xa - diag - mxv) + PEPS);
    const float pb = hb ? RATIO*(__expf(xb - diag - mxv) + PEPS) : 0.f;
    phi4[wv][m_a] = pa;
    if (hb) phi4[wv][m_b] = pb;
    float dn = wredsum(pa*ksa + pb*ksb);
    const float rden = 1.f / dn;
    float acc = 0.f;
    #pragma unroll
    for (int jj=0; jj<14; jj++){
      float4 ph = *(const float4*)&phi4[wv][half*56 + jj*4];
      acc += ph.x*ctxc[jj*4] + ph.y*ctxc[jj*4+1] + ph.z*ctxc[jj*4+2] + ph.w*ctxc[jj*4+3];
    }
    acc += __shfl_xor(acc, 32);
    if (lane < 32) Og[qoff + lane] = f2bf(acc * rden);
  }
}

// ---------------- z accumulation ----------------
__global__ __launch_bounds__(256) void zacc_k(
    const float* __restrict__ X, const float* __restrict__ fw,
    const float* __restrict__ fb, float* __restrict__ Z, int mode)
{
  int tid=threadIdx.x, w=tid>>6, lane=tid&63;
  int row = blockIdx.x*4 + w;
  int b = row/SEQ, t = row%SEQ;
  int tt = t;
  if (mode == 1) {
    int l = t/192, r = t%192;
    tt = r*8 + l;
  }
  const float4 x0 = *(const float4*)&X[((size_t)b*SEQ + tt)*DM + lane*4];
  const float4 f4 = *(const float4*)&fw[lane*4];
  float ssum = x0.x*f4.x + x0.y*f4.y + x0.z*f4.z + x0.w*f4.w;
  ssum = wredsum(ssum);
  if (lane==0) {
    if (mode == 0) Z[row] = ssum + fb[0];
    else           Z[row] += ssum;
  }
}

// ---------------- out = z @ out_w + out_b ----------------
__global__ __launch_bounds__(256) void out_k(
    const float* __restrict__ Z, const float* __restrict__ outw,
    const float* __restrict__ outb, float* __restrict__ out)
{
  int b = blockIdx.x; int tid = threadIdx.x;
  float4 acc = make_float4(0.f,0.f,0.f,0.f);
  const float* zrow = Z + (size_t)b*SEQ;
  for (int t=0;t<SEQ;t++){
    float zv = zrow[t];
    float4 wv = *(const float4*)&outw[(size_t)t*1024 + tid*4];
    acc.x += zv*wv.x; acc.y += zv*wv.y; acc.z += zv*wv.z; acc.w += zv*wv.w;
  }
  float4 ob = *(const float4*)&outb[tid*4];
  float4 o = make_float4(acc.x+ob.x, acc.y+ob.y, acc.z+ob.z, acc.w+ob.w);
  *(float4*)&out[(size_t)b*1024 + tid*4] = o;
}

extern "C" void kernel_launch(void* const* d_in, const int* in_sizes, int n_in,
                              void* d_out, int out_size, void* d_ws, size_t ws_size,
                              hipStream_t stream) {
  (void)in_sizes; (void)n_in;
  const float* mag  = (const float*)d_in[0];
  const float* syn  = (const float*)d_in[1];
  const float* magT = (const float*)d_in[2];
  const float* synT = (const float*)d_in[3];
  const float* se   = (const float*)d_in[4];
  const float* seT  = (const float*)d_in[5];
  const float* ln1s = (const float*)d_in[6];
  const float* ln1b = (const float*)d_in[7];
  const float* Wq   = (const float*)d_in[8];
  const float* bq   = (const float*)d_in[9];
  const float* Wk   = (const float*)d_in[10];
  const float* bk   = (const float*)d_in[11];
  const float* Wv   = (const float*)d_in[12];
  const float* bv   = (const float*)d_in[13];
  const float* Wo   = (const float*)d_in[14];
  const float* bo   = (const float*)d_in[15];
  const float* proj = (const float*)d_in[16];
  const float* ln2s = (const float*)d_in[17];
  const float* ln2b = (const float*)d_in[18];
  const float* W1   = (const float*)d_in[19];
  const float* b1   = (const float*)d_in[20];
  const float* W2   = (const float*)d_in[21];
  const float* b2   = (const float*)d_in[22];
  const float* fw   = (const float*)d_in[23];
  const float* fb   = (const float*)d_in[24];
  const float* outw = (const float*)d_in[25];
  const float* outb = (const float*)d_in[26];
  float* out = (float*)d_out;

  // ---- workspace layout (bytes) ----
  char* base = (char*)d_ws;
  const size_t PANEL = (size_t)RB*DM;
  size_t off = 0;
  float* X   = (float*)(base + off); off += PANEL*4;
  float* Y1  = (float*)(base + off); off += PANEL*4;   // also PART buffer during attention
  u16*  Hb   = (u16*)(base + off);   off += PANEL*2;
  u16*  Qb   = (u16*)(base + off);   off += PANEL*2;   // FFI spans Qb+Kb (RB x 512)
  u16*  Kb   = (u16*)(base + off);   off += PANEL*2;
  u16*  Vb   = (u16*)(base + off);   off += PANEL*2;
  u16*  Wts  = (u16*)(base + off);   off += (size_t)12*524288*2;
  float* CTXb= (float*)(base + off); off += (size_t)256*MF*32*4;
  float* KSb = (float*)(base + off); off += (size_t)256*MF*4;
  float* PMb = (float*)(base + off); off += (size_t)256*NCH*4;
  float* Zb  = (float*)(base + off); off += (size_t)BSZ*SEQ*4;
  if (ws_size < off) {
    float v = 100000.0f + (float)(ws_size >> 20);
    sentinel_k<<<dim3((out_size+255)/256), 256, 0, stream>>>(out, out_size, v);
    return;
  }
  float* PARTb = Y1;   // [NCH][256][MF][36] = 48.6 MB (Y1 dead during attention)
  const size_t WST = 524288;

  // ---- transpose+convert all weights ----
  wtrans_k<<<dim3(8,8,12),  256, 0, stream>>>(Wq, Wts + 0,      256, 256, WST);
  wtrans_k<<<dim3(8,8,12),  256, 0, stream>>>(Wk, Wts + 65536,  256, 256, WST);
  wtrans_k<<<dim3(8,8,12),  256, 0, stream>>>(Wv, Wts + 131072, 256, 256, WST);
  wtrans_k<<<dim3(8,8,12),  256, 0, stream>>>(Wo, Wts + 196608, 256, 256, WST);
  wtrans_k<<<dim3(16,8,12), 256, 0, stream>>>(W1, Wts + 262144, 256, 512, WST);
  wtrans_k<<<dim3(8,16,12), 256, 0, stream>>>(W2, Wts + 393216, 512, 256, WST);

  for (int s=0; s<2; s++){
    embed_k<<<dim3(RB/4), 256, 0, stream>>>(mag, syn, magT, synT, se, seT, X, s);
    for (int l=0; l<NL; l++){
      int wi = s*NL + l;
      const u16* Wqt = Wts + (size_t)wi*WST;
      const u16* Wkt = Wqt + 65536;
      const u16* Wvt = Wqt + 131072;
      const u16* Wot = Wqt + 196608;
      const u16* W1t = Wqt + 262144;
      const u16* W2t = Wqt + 393216;
      const float* pproj = proj + (size_t)wi*MF*DH;

      ln_k<<<dim3(RB/4), 256, 0, stream>>>(X, Hb, ln1s + (size_t)wi*DM, ln1b + (size_t)wi*DM);
      mgemm_k<<<dim3(4,384), 256, 0, stream>>>(Hb, Wqt, bq + (size_t)wi*DM, Qb, nullptr, nullptr, 256, 256, 0);
      mgemm_k<<<dim3(4,384), 256, 0, stream>>>(Hb, Wkt, bk + (size_t)wi*DM, Kb, nullptr, nullptr, 256, 256, 0);
      mgemm_k<<<dim3(4,384), 256, 0, stream>>>(Hb, Wvt, bv + (size_t)wi*DM, Vb, nullptr, nullptr, 256, 256, 0);
      ctxmax_k<<<dim3(NH,BSZ,NCH), 128, 0, stream>>>(Kb, pproj, PMb);
      ctxacc_k<<<dim3(NH,BSZ,NCH), 128, 0, stream>>>(Kb, Vb, pproj, PMb, PARTb);
      ctxred_k<<<dim3(MF*36), 256, 0, stream>>>(PARTb, CTXb, KSb);
      o_k<<<dim3(SEQ/128, NH, BSZ), 256, 0, stream>>>(Qb, pproj, CTXb, KSb, Hb);
      mgemm_k<<<dim3(4,384), 256, 0, stream>>>(Hb, Wot, bo + (size_t)wi*DM, Y1, X, nullptr, 256, 256, 1);
      ln_k<<<dim3(RB/4), 256, 0, stream>>>(Y1, Hb, ln2s + (size_t)wi*DM, ln2b + (size_t)wi*DM);
      mgemm_k<<<dim3(8,384), 256, 0, stream>>>(Hb, W1t, b1 + (size_t)wi*512, Qb, nullptr, nullptr, 256, 512, 2);
      mgemm_k<<<dim3(4,384), 256, 0, stream>>>(Qb, W2t, b2 + (size_t)wi*DM, X, X, Y1, 512, 256, 3);
    }
    zacc_k<<<dim3(RB/4), 256, 0, stream>>>(X, fw, fb, Zb, s);
  }

  out_k<<<dim3(BSZ), 256, 0, stream>>>(Zb, outw, outb, out);
}